// Round 3
// baseline (108.078 us; speedup 1.0000x reference)
//
#include <hip/hip_runtime.h>
#include <hip/hip_bf16.h>

typedef __bf16 bf16_t;
typedef __bf16 bf16x8 __attribute__((ext_vector_type(8)));
typedef __bf16 bf16x4 __attribute__((ext_vector_type(4)));
typedef float  f32x4  __attribute__((ext_vector_type(4)));

#define MFMA_BF16(A, B, C) __builtin_amdgcn_mfma_f32_16x16x32_bf16((A), (B), (C), 0, 0, 0)

#define BATCH 8
#define SEQ   2048
#define EMB   1024
#define HEAD  64

// ---------------------------------------------------------------------------
// Kernel 0: W [1024][64] fp32 x3  ->  WT bf16 [192][1024]  (transposed),
// with softmax scale 1/sqrt(1024) = 1/32 folded into Wq.
// ---------------------------------------------------------------------------
__global__ __launch_bounds__(256) void wtrans_kernel(
    const float* __restrict__ Wq, const float* __restrict__ Wk,
    const float* __restrict__ Wv, bf16_t* __restrict__ WT)
{
  __shared__ float tile[64][65];
  const int m  = blockIdx.x >> 4;                // 0..2 -> q,k,v
  const int kt = blockIdx.x & 15;                // 64-row chunk of K dim
  const float* W = (m == 0) ? Wq : (m == 1) ? Wk : Wv;
  const float scale = (m == 0) ? 0.03125f : 1.0f;
  const int k0 = kt * 64;

  #pragma unroll
  for (int i = 0; i < 16; ++i) {
    int idx = i * 256 + threadIdx.x;
    int kk = idx >> 6, n = idx & 63;
    tile[kk][n] = W[(size_t)(k0 + kk) * HEAD + n];
  }
  __syncthreads();
  #pragma unroll
  for (int i = 0; i < 16; ++i) {
    int idx = i * 256 + threadIdx.x;
    int n = idx >> 6, kk = idx & 63;
    WT[((size_t)m * HEAD + n) * EMB + k0 + kk] = (bf16_t)(tile[kk][n] * scale);
  }
}

// ---------------------------------------------------------------------------
// Kernel 1: fused q/k/v projection, v3.
// 512 blocks = 256 row-blocks x 2 col-halves. 4 waves/block; wave = 16 rows
// x 96 cols, FULL K (no reduction, no LDS). Only 6 accs (24 VGPR) ->
// launch_bounds(256,2) grants 256 VGPR -> explicit next-iter prefetch of x
// and B-frags gives deep MLP. Col-half twin blocks land on the same XCD
// concurrently (bid swizzle) so x is HBM-fetched once, L2-hit the 2nd time.
// WT L2 traffic: 512 x 192KB = 98 MB (4x less than v2).
// ---------------------------------------------------------------------------
__global__ __launch_bounds__(256, 2) void qkv_kernel(
    const float* __restrict__ x, const bf16_t* __restrict__ WT,
    bf16_t* __restrict__ qo, bf16_t* __restrict__ ko, bf16_t* __restrict__ vT)
{
  const int lane = threadIdx.x & 63;
  const int wave = threadIdx.x >> 6;
  const int l15 = lane & 15, l4 = lane >> 4;

  const int bid = blockIdx.x;
  const int ch       = (bid >> 3) & 1;                    // col-half: 0 -> cols 0..95, 1 -> 96..191
  const int rowblock = ((bid >> 4) << 3) | (bid & 7);     // twin blocks (ch 0/1) -> same XCD, ~same time
  const int rowbase  = rowblock * 64 + wave * 16;

  const float*  xr = x  + (size_t)(rowbase + l15) * EMB + l4 * 8;
  const bf16_t* wp = WT + (size_t)(ch * 96 + l15) * EMB + l4 * 8;

  f32x4 acc[6];
  #pragma unroll
  for (int i = 0; i < 6; ++i) acc[i] = (f32x4){0.f, 0.f, 0.f, 0.f};

  // prologue: first x pair + first B-frags
  float4 xf0 = *(const float4*)(xr);
  float4 xf1 = *(const float4*)(xr + 4);
  bf16x8 bf[6];
  #pragma unroll
  for (int nf = 0; nf < 6; ++nf) bf[nf] = *(const bf16x8*)(wp + (size_t)nf * 16 * EMB);

  #pragma unroll
  for (int k0 = 0; k0 < EMB - 32; k0 += 32) {
    // prefetch next iteration (independent of current MFMAs)
    float4 nx0 = *(const float4*)(xr + k0 + 32);
    float4 nx1 = *(const float4*)(xr + k0 + 36);
    bf16x8 nb[6];
    #pragma unroll
    for (int nf = 0; nf < 6; ++nf)
      nb[nf] = *(const bf16x8*)(wp + (size_t)nf * 16 * EMB + k0 + 32);

    bf16x8 a;
    a[0] = (bf16_t)xf0.x; a[1] = (bf16_t)xf0.y; a[2] = (bf16_t)xf0.z; a[3] = (bf16_t)xf0.w;
    a[4] = (bf16_t)xf1.x; a[5] = (bf16_t)xf1.y; a[6] = (bf16_t)xf1.z; a[7] = (bf16_t)xf1.w;
    #pragma unroll
    for (int nf = 0; nf < 6; ++nf) acc[nf] = MFMA_BF16(a, bf[nf], acc[nf]);

    xf0 = nx0; xf1 = nx1;
    #pragma unroll
    for (int nf = 0; nf < 6; ++nf) bf[nf] = nb[nf];
  }
  { // last iteration
    bf16x8 a;
    a[0] = (bf16_t)xf0.x; a[1] = (bf16_t)xf0.y; a[2] = (bf16_t)xf0.z; a[3] = (bf16_t)xf0.w;
    a[4] = (bf16_t)xf1.x; a[5] = (bf16_t)xf1.y; a[6] = (bf16_t)xf1.z; a[7] = (bf16_t)xf1.w;
    #pragma unroll
    for (int nf = 0; nf < 6; ++nf) acc[nf] = MFMA_BF16(a, bf[nf], acc[nf]);
  }

  // Epilogue. D layout: row = l4*4+i, col = nf*16+l15 (m89-verified).
  // Global col c = ch*96 + nf*16 + l15:  c<64 -> q, 64<=c<128 -> k, else v^T.
  if (ch == 0) {
    #pragma unroll
    for (int nf = 0; nf < 4; ++nf)
      #pragma unroll
      for (int i = 0; i < 4; ++i)
        qo[((size_t)rowbase + l4 * 4 + i) * HEAD + nf * 16 + l15] = (bf16_t)acc[nf][i];
    #pragma unroll
    for (int nf = 4; nf < 6; ++nf)
      #pragma unroll
      for (int i = 0; i < 4; ++i)
        ko[((size_t)rowbase + l4 * 4 + i) * HEAD + (nf - 4) * 16 + l15] = (bf16_t)acc[nf][i];
  } else {
    #pragma unroll
    for (int nf = 0; nf < 2; ++nf)
      #pragma unroll
      for (int i = 0; i < 4; ++i)
        ko[((size_t)rowbase + l4 * 4 + i) * HEAD + 32 + nf * 16 + l15] = (bf16_t)acc[nf][i];
    const int b    = rowbase >> 11;              // 16-row tile never crosses a batch
    const int tloc = (rowbase & 2047) + l4 * 4;
    #pragma unroll
    for (int nf = 2; nf < 6; ++nf) {
      const int h = (nf - 2) * 16 + l15;
      bf16x4 pk;
      #pragma unroll
      for (int i = 0; i < 4; ++i) pk[i] = (bf16_t)acc[nf][i];
      *(bf16x4*)(vT + ((size_t)b * HEAD + h) * SEQ + tloc) = pk;   // 8B store
    }
  }
}

// ---------------------------------------------------------------------------
// Kernel 2: causal attention, KEY-SPLIT across 4 waves per block (unchanged).
// ---------------------------------------------------------------------------
__global__ __launch_bounds__(256) void attn_kernel(
    const bf16_t* __restrict__ q, const bf16_t* __restrict__ k,
    const bf16_t* __restrict__ vT, float* __restrict__ out)
{
  __shared__ bf16_t P[4][16][72];                // per-wave P tile
  __shared__ float olds[4][16][68];              // per-wave O partials
  __shared__ float lsums[4][16];                 // per-wave row-sum partials
  const int lane = threadIdx.x & 63;
  const int wave = threadIdx.x >> 6;
  const int l15 = lane & 15, l4 = lane >> 4;
  const int batch = blockIdx.x & 7;
  const int strip = 127 - (int)(blockIdx.x >> 3);
  const int qrow  = strip * 16;

  const bf16_t* qb = q  + ((size_t)batch * SEQ + qrow) * HEAD;
  const bf16_t* kb = k  + (size_t)batch * SEQ * HEAD;
  const bf16_t* vb = vT + (size_t)batch * HEAD * SEQ;

  bf16x8 aq0 = *(const bf16x8*)(qb + (size_t)l15 * HEAD + l4 * 8);
  bf16x8 aq1 = *(const bf16x8*)(qb + (size_t)l15 * HEAD + 32 + l4 * 8);

  f32x4 o[4];
  #pragma unroll
  for (int i = 0; i < 4; ++i) o[i] = (f32x4){0.f, 0.f, 0.f, 0.f};
  float lsum[4] = {0.f, 0.f, 0.f, 0.f};

  const int ntiles = (qrow >> 6) + 1;
  for (int t = wave; t < ntiles; t += 4) {
    const int kv0 = t * 64;

    f32x4 s[4];
    #pragma unroll
    for (int nf = 0; nf < 4; ++nf) s[nf] = (f32x4){0.f, 0.f, 0.f, 0.f};
    #pragma unroll
    for (int nf = 0; nf < 4; ++nf) {
      const bf16_t* kp = kb + (size_t)(kv0 + nf * 16 + l15) * HEAD + l4 * 8;
      bf16x8 b0 = *(const bf16x8*)kp;
      bf16x8 b1 = *(const bf16x8*)(kp + 32);
      s[nf] = MFMA_BF16(aq0, b0, s[nf]);
      s[nf] = MFMA_BF16(aq1, b1, s[nf]);
    }

    const bool diag = (t == ntiles - 1);
    #pragma unroll
    for (int nf = 0; nf < 4; ++nf) {
      #pragma unroll
      for (int i = 0; i < 4; ++i) {
        float e = __expf(s[nf][i]);
        if (diag) {
          const int col = kv0 + nf * 16 + l15;
          const int row = qrow + l4 * 4 + i;
          e = (col <= row) ? e : 0.f;
        }
        lsum[i] += e;
        P[wave][l4 * 4 + i][nf * 16 + l15] = (bf16_t)e;
      }
    }
    asm volatile("s_waitcnt lgkmcnt(0)" ::: "memory");

    bf16x8 ap0 = *(const bf16x8*)&P[wave][l15][l4 * 8];
    bf16x8 ap1 = *(const bf16x8*)&P[wave][l15][32 + l4 * 8];
    #pragma unroll
    for (int nf = 0; nf < 4; ++nf) {
      const bf16_t* vp = vb + (size_t)(nf * 16 + l15) * SEQ + kv0 + l4 * 8;
      bf16x8 b0 = *(const bf16x8*)vp;
      bf16x8 b1 = *(const bf16x8*)(vp + 32);
      o[nf] = MFMA_BF16(ap0, b0, o[nf]);
      o[nf] = MFMA_BF16(ap1, b1, o[nf]);
    }
  }

  #pragma unroll
  for (int i = 0; i < 4; ++i) {
    float v = lsum[i];
    v += __shfl_xor(v, 1);
    v += __shfl_xor(v, 2);
    v += __shfl_xor(v, 4);
    v += __shfl_xor(v, 8);
    if (l15 == 0) lsums[wave][l4 * 4 + i] = v;
  }
  #pragma unroll
  for (int nf = 0; nf < 4; ++nf)
    #pragma unroll
    for (int i = 0; i < 4; ++i)
      olds[wave][l4 * 4 + i][nf * 16 + l15] = o[nf][i];
  __syncthreads();

  {
    const int t = threadIdx.x;
    const int r = t >> 4, c0 = t & 15;
    const float s = lsums[0][r] + lsums[1][r] + lsums[2][r] + lsums[3][r];
    const float rinv = 1.0f / s;
    float* ob = out + ((size_t)batch * SEQ + qrow + r) * HEAD;
    #pragma unroll
    for (int j = 0; j < 4; ++j) {
      const int c = c0 + 16 * j;
      float v = olds[0][r][c] + olds[1][r][c] + olds[2][r][c] + olds[3][r][c];
      ob[c] = v * rinv;
    }
  }
}

// ---------------------------------------------------------------------------
extern "C" void kernel_launch(void* const* d_in, const int* in_sizes, int n_in,
                              void* d_out, int out_size, void* d_ws, size_t ws_size,
                              hipStream_t stream)
{
  const float* x  = (const float*)d_in[0];
  const float* Wq = (const float*)d_in[1];
  const float* Wk = (const float*)d_in[2];
  const float* Wv = (const float*)d_in[3];
  float* out = (float*)d_out;

  const size_t SZ_QKV = (size_t)BATCH * SEQ * HEAD * sizeof(bf16_t);   // 2 MiB
  if (ws_size < 3 * SZ_QKV + (size_t)192 * EMB * sizeof(bf16_t)) return;
  char* ws = (char*)d_ws;
  bf16_t* qo = (bf16_t*)(ws);
  bf16_t* ko = (bf16_t*)(ws + SZ_QKV);
  bf16_t* vT = (bf16_t*)(ws + 2 * SZ_QKV);
  bf16_t* WT = (bf16_t*)(ws + 3 * SZ_QKV);

  wtrans_kernel<<<dim3(48),   dim3(256), 0, stream>>>(Wq, Wk, Wv, WT);
  qkv_kernel  <<<dim3(512),  dim3(256), 0, stream>>>(x, WT, qo, ko, vT);
  attn_kernel <<<dim3(1024), dim3(256), 0, stream>>>(qo, ko, vT, out);
}

// Round 4
// 71.107 us; speedup vs baseline: 1.5199x; 1.5199x over previous
//
#include <hip/hip_runtime.h>
#include <hip/hip_bf16.h>

typedef __bf16 bf16_t;
typedef __bf16 bf16x8 __attribute__((ext_vector_type(8)));
typedef __bf16 bf16x4 __attribute__((ext_vector_type(4)));
typedef float  f32x4  __attribute__((ext_vector_type(4)));

#define MFMA_BF16(A, B, C) __builtin_amdgcn_mfma_f32_16x16x32_bf16((A), (B), (C), 0, 0, 0)

#define BATCH 8
#define SEQ   2048
#define EMB   1024
#define HEAD  64

// global_load_lds address-space plumbing (HW: LDS dest = wave-uniform base + lane*16)
typedef __attribute__((address_space(3))) void as3_void;
typedef const __attribute__((address_space(1))) void as1_void;
#define GLOAD_LDS16(g, l) \
  __builtin_amdgcn_global_load_lds((as1_void*)(g), (as3_void*)(l), 16, 0, 0)

// ---------------------------------------------------------------------------
// Kernel 0: W [1024][64] fp32 x3 -> WT bf16 [192][1024] (transposed),
// softmax scale 1/32 folded into Wq.
// ---------------------------------------------------------------------------
__global__ __launch_bounds__(256) void wtrans_kernel(
    const float* __restrict__ Wq, const float* __restrict__ Wk,
    const float* __restrict__ Wv, bf16_t* __restrict__ WT)
{
  __shared__ float tile[64][65];
  const int m  = blockIdx.x >> 4;
  const int kt = blockIdx.x & 15;
  const float* W = (m == 0) ? Wq : (m == 1) ? Wk : Wv;
  const float scale = (m == 0) ? 0.03125f : 1.0f;
  const int k0 = kt * 64;

  #pragma unroll
  for (int i = 0; i < 16; ++i) {
    int idx = i * 256 + threadIdx.x;
    int kk = idx >> 6, n = idx & 63;
    tile[kk][n] = W[(size_t)(k0 + kk) * HEAD + n];
  }
  __syncthreads();
  #pragma unroll
  for (int i = 0; i < 16; ++i) {
    int idx = i * 256 + threadIdx.x;
    int n = idx >> 6, kk = idx & 63;
    WT[((size_t)m * HEAD + n) * EMB + k0 + kk] = (bf16_t)(tile[kk][n] * scale);
  }
}

// ---------------------------------------------------------------------------
// Kernel 1: qkv v4 — 2-phase LDS-double-buffered GEMM (T3 minimum recipe).
// BM=64, BN=96, BK=64; 512 blocks = 256 rowblocks x 2 col-halves; 4 waves
// (2M x 2N), wave = 32 rows x 48 cols, 16 K-steps.
//   B: global_load_lds(16B) direct, source pre-swizzled (rule #21).
//   A: reg-staged fp32->bf16 (T14 split: load early, cvt+ds_write late).
// LDS rows are 128B; XOR swizzle byte^=((row&7)<<4) => reads 2-way (free).
// ---------------------------------------------------------------------------
__global__ __launch_bounds__(256, 4) void qkv_kernel(
    const float* __restrict__ x, const bf16_t* __restrict__ WT,
    bf16_t* __restrict__ qo, bf16_t* __restrict__ ko, bf16_t* __restrict__ vT)
{
  __shared__ bf16_t As[2][64 * 64];   // [row][k] 128B rows, swizzled
  __shared__ bf16_t Bs[2][96 * 64];   // [col][k] 128B rows, swizzled

  const int tid  = threadIdx.x;
  const int lane = tid & 63;
  const int wave = tid >> 6;
  const int l15 = lane & 15, l4 = lane >> 4;
  const int wm = wave >> 1, wn = wave & 1;

  const int ch       = blockIdx.x & 1;
  const int rowblock = blockIdx.x >> 1;
  const int rowbase  = rowblock * 64;

  // ---- A stage mapping: thread -> row ra, 4x float4 at cols (tid&3)*4 + i*16
  const int ra = tid >> 2;
  const int ca = (tid & 3) * 4;
  const float* xsrc = x + (size_t)(rowbase + ra) * EMB + ca;
  const int aswz = (ra & 7) << 4;
  char* Arow[2] = { (char*)&As[0][0] + ra * 128, (char*)&As[1][0] + ra * 128 };

  // ---- B DMA mapping: instr i covers rows 8i + (lane>>3), slot (lane&7)*16B;
  // source col-offset pre-swizzled so linear LDS + swizzled read match.
  const int brow_sub = lane >> 3;                       // row within instr group
  const int bsrc_off = ((lane & 7) * 16) ^ (brow_sub << 4);  // bytes in 128B row
  const bf16_t* wbase = WT + (size_t)ch * 96 * EMB + (bsrc_off >> 1);

  // read-side swizzled k-offsets (bits 4..6 only -> XOR is safe on full addr)
  const int rswz = (l15 & 7) << 4;

  f32x4 acc[2][3];
  #pragma unroll
  for (int m = 0; m < 2; ++m)
    #pragma unroll
    for (int n = 0; n < 3; ++n) acc[m][n] = (f32x4){0.f, 0.f, 0.f, 0.f};

  // ---- prologue: stage step 0 into buf 0
  {
    float4 af[4];
    #pragma unroll
    for (int i = 0; i < 4; ++i) af[i] = *(const float4*)(xsrc + i * 16);
    #pragma unroll
    for (int j = 0; j < 3; ++j) {
      const int bi = wave * 3 + j;
      const bf16_t* g = wbase + (size_t)(8 * bi + brow_sub) * EMB;
      GLOAD_LDS16(g, &Bs[0][bi * 512]);
    }
    #pragma unroll
    for (int i = 0; i < 4; ++i) {
      bf16x4 w;
      w[0] = (bf16_t)af[i].x; w[1] = (bf16_t)af[i].y;
      w[2] = (bf16_t)af[i].z; w[3] = (bf16_t)af[i].w;
      *(bf16x4*)(Arow[0] + (((ca + i * 16) * 2) ^ aswz)) = w;
    }
  }
  __syncthreads();

  for (int kt = 0; kt < 16; ++kt) {
    const int cur = kt & 1, nxt = cur ^ 1;
    const bool more = (kt + 1 < 16);

    // phase 1: issue next tile's loads (async)
    float4 af[4];
    if (more) {
      const int k0n = (kt + 1) * 64;
      #pragma unroll
      for (int i = 0; i < 4; ++i) af[i] = *(const float4*)(xsrc + k0n + i * 16);
      #pragma unroll
      for (int j = 0; j < 3; ++j) {
        const int bi = wave * 3 + j;
        const bf16_t* g = wbase + (size_t)(8 * bi + brow_sub) * EMB + k0n;
        GLOAD_LDS16(g, &Bs[nxt][bi * 512]);
      }
    }

    // phase 2: compute current tile from LDS
    const char* Ab = (const char*)&As[cur][0];
    const char* Bb = (const char*)&Bs[cur][0];
    #pragma unroll
    for (int ksub = 0; ksub < 2; ++ksub) {
      const int coff = (ksub * 64 + l4 * 16) ^ rswz;
      bf16x8 a0 = *(const bf16x8*)(Ab + (wm * 32 + l15) * 128 + coff);
      bf16x8 a1 = *(const bf16x8*)(Ab + (wm * 32 + 16 + l15) * 128 + coff);
      #pragma unroll
      for (int n = 0; n < 3; ++n) {
        bf16x8 b = *(const bf16x8*)(Bb + (wn * 48 + n * 16 + l15) * 128 + coff);
        acc[0][n] = MFMA_BF16(a0, b, acc[0][n]);
        acc[1][n] = MFMA_BF16(a1, b, acc[1][n]);
      }
    }

    // phase 3: write A-next (vmcnt wait hidden under MFMAs), then barrier
    if (more) {
      #pragma unroll
      for (int i = 0; i < 4; ++i) {
        bf16x4 w;
        w[0] = (bf16_t)af[i].x; w[1] = (bf16_t)af[i].y;
        w[2] = (bf16_t)af[i].z; w[3] = (bf16_t)af[i].w;
        *(bf16x4*)(Arow[nxt] + (((ca + i * 16) * 2) ^ aswz)) = w;
      }
    }
    __syncthreads();
  }

  // ---- epilogue: D row = l4*4+i, col = nf*16+l15 (m89-verified)
  #pragma unroll
  for (int n = 0; n < 3; ++n) {
    const int base = ch * 96 + wn * 48 + n * 16;   // wave-uniform
    #pragma unroll
    for (int m = 0; m < 2; ++m) {
      const int r0 = rowbase + wm * 32 + m * 16 + l4 * 4;
      if (base < 64) {
        #pragma unroll
        for (int i = 0; i < 4; ++i)
          qo[(size_t)(r0 + i) * HEAD + base + l15] = (bf16_t)acc[m][n][i];
      } else if (base < 128) {
        #pragma unroll
        for (int i = 0; i < 4; ++i)
          ko[(size_t)(r0 + i) * HEAD + base - 64 + l15] = (bf16_t)acc[m][n][i];
      } else {
        const int h = base - 128 + l15;
        bf16x4 pk;
        #pragma unroll
        for (int i = 0; i < 4; ++i) pk[i] = (bf16_t)acc[m][n][i];
        *(bf16x4*)(vT + ((size_t)(r0 >> 11) * HEAD + h) * SEQ + (r0 & 2047)) = pk;
      }
    }
  }
}

// ---------------------------------------------------------------------------
// Kernel 2: attn v3 — strip-PAIRED blocks (uniform work), 8 waves.
// Block = (strip p, strip 127-p): waves 0-3 K-split strip A, 4-7 strip B.
// V-frags loaded at tile start so their L2 latency hides under QK+exp.
// ---------------------------------------------------------------------------
__global__ __launch_bounds__(512, 4) void attn_kernel(
    const bf16_t* __restrict__ q, const bf16_t* __restrict__ k,
    const bf16_t* __restrict__ vT, float* __restrict__ out)
{
  __shared__ bf16_t P[8][16][72];
  __shared__ float olds[8][16][68];
  __shared__ float lsums[8][16];
  const int lane = threadIdx.x & 63;
  const int wave = threadIdx.x >> 6;
  const int l15 = lane & 15, l4 = lane >> 4;
  const int batch = blockIdx.x & 7;
  const int pair  = blockIdx.x >> 3;             // 0..63
  const int strip = (wave < 4) ? pair : (127 - pair);
  const int wsub  = wave & 3;
  const int qrow  = strip * 16;

  const bf16_t* qb = q  + ((size_t)batch * SEQ + qrow) * HEAD;
  const bf16_t* kb = k  + (size_t)batch * SEQ * HEAD;
  const bf16_t* vb = vT + (size_t)batch * HEAD * SEQ;

  bf16x8 aq0 = *(const bf16x8*)(qb + (size_t)l15 * HEAD + l4 * 8);
  bf16x8 aq1 = *(const bf16x8*)(qb + (size_t)l15 * HEAD + 32 + l4 * 8);

  f32x4 o[4];
  #pragma unroll
  for (int i = 0; i < 4; ++i) o[i] = (f32x4){0.f, 0.f, 0.f, 0.f};
  float lsum[4] = {0.f, 0.f, 0.f, 0.f};

  const int ntiles = (qrow >> 6) + 1;
  for (int t = wsub; t < ntiles; t += 4) {
    const int kv0 = t * 64;

    // V early (independent; consumed after exp -> latency hidden)
    bf16x8 v0[4], v1[4];
    #pragma unroll
    for (int nf = 0; nf < 4; ++nf) {
      const bf16_t* vp = vb + (size_t)(nf * 16 + l15) * SEQ + kv0 + l4 * 8;
      v0[nf] = *(const bf16x8*)vp;
      v1[nf] = *(const bf16x8*)(vp + 32);
    }

    f32x4 s[4];
    #pragma unroll
    for (int nf = 0; nf < 4; ++nf) s[nf] = (f32x4){0.f, 0.f, 0.f, 0.f};
    #pragma unroll
    for (int nf = 0; nf < 4; ++nf) {
      const bf16_t* kp = kb + (size_t)(kv0 + nf * 16 + l15) * HEAD + l4 * 8;
      bf16x8 b0 = *(const bf16x8*)kp;
      bf16x8 b1 = *(const bf16x8*)(kp + 32);
      s[nf] = MFMA_BF16(aq0, b0, s[nf]);
      s[nf] = MFMA_BF16(aq1, b1, s[nf]);
    }

    const bool diag = (t == ntiles - 1);
    #pragma unroll
    for (int nf = 0; nf < 4; ++nf) {
      #pragma unroll
      for (int i = 0; i < 4; ++i) {
        float e = __expf(s[nf][i]);
        if (diag) {
          const int col = kv0 + nf * 16 + l15;
          const int row = qrow + l4 * 4 + i;
          e = (col <= row) ? e : 0.f;
        }
        lsum[i] += e;
        P[wave][l4 * 4 + i][nf * 16 + l15] = (bf16_t)e;
      }
    }
    asm volatile("s_waitcnt lgkmcnt(0)" ::: "memory");

    bf16x8 ap0 = *(const bf16x8*)&P[wave][l15][l4 * 8];
    bf16x8 ap1 = *(const bf16x8*)&P[wave][l15][32 + l4 * 8];
    #pragma unroll
    for (int nf = 0; nf < 4; ++nf) {
      o[nf] = MFMA_BF16(ap0, v0[nf], o[nf]);
      o[nf] = MFMA_BF16(ap1, v1[nf], o[nf]);
    }
  }

  // publish per-wave partials
  #pragma unroll
  for (int i = 0; i < 4; ++i) {
    float v = lsum[i];
    v += __shfl_xor(v, 1);
    v += __shfl_xor(v, 2);
    v += __shfl_xor(v, 4);
    v += __shfl_xor(v, 8);
    if (l15 == 0) lsums[wave][l4 * 4 + i] = v;
  }
  #pragma unroll
  for (int nf = 0; nf < 4; ++nf)
    #pragma unroll
    for (int i = 0; i < 4; ++i)
      olds[wave][l4 * 4 + i][nf * 16 + l15] = o[nf][i];
  __syncthreads();

  // cross-wave reduce: threads 0-255 -> strip A, 256-511 -> strip B
  {
    const int g  = threadIdx.x >> 8;
    const int tt = threadIdx.x & 255;
    const int r = tt >> 4, c0 = tt & 15;
    const int sstrip = g ? (127 - pair) : pair;
    const int w0 = g * 4;
    const float s = lsums[w0][r] + lsums[w0+1][r] + lsums[w0+2][r] + lsums[w0+3][r];
    const float rinv = 1.0f / s;
    float* ob = out + ((size_t)batch * SEQ + sstrip * 16 + r) * HEAD;
    #pragma unroll
    for (int j = 0; j < 4; ++j) {
      const int c = c0 + 16 * j;
      float v = olds[w0][r][c] + olds[w0+1][r][c] + olds[w0+2][r][c] + olds[w0+3][r][c];
      ob[c] = v * rinv;
    }
  }
}

// ---------------------------------------------------------------------------
extern "C" void kernel_launch(void* const* d_in, const int* in_sizes, int n_in,
                              void* d_out, int out_size, void* d_ws, size_t ws_size,
                              hipStream_t stream)
{
  const float* x  = (const float*)d_in[0];
  const float* Wq = (const float*)d_in[1];
  const float* Wk = (const float*)d_in[2];
  const float* Wv = (const float*)d_in[3];
  float* out = (float*)d_out;

  const size_t SZ_QKV = (size_t)BATCH * SEQ * HEAD * sizeof(bf16_t);   // 2 MiB
  if (ws_size < 3 * SZ_QKV + (size_t)192 * EMB * sizeof(bf16_t)) return;
  char* ws = (char*)d_ws;
  bf16_t* qo = (bf16_t*)(ws);
  bf16_t* ko = (bf16_t*)(ws + SZ_QKV);
  bf16_t* vT = (bf16_t*)(ws + 2 * SZ_QKV);
  bf16_t* WT = (bf16_t*)(ws + 3 * SZ_QKV);

  wtrans_kernel<<<dim3(48),  dim3(256), 0, stream>>>(Wq, Wk, Wv, WT);
  qkv_kernel  <<<dim3(512), dim3(256), 0, stream>>>(x, WT, qo, ko, vT);
  attn_kernel <<<dim3(512), dim3(512), 0, stream>>>(qo, ko, vT, out);
}